// Round 9
// baseline (119.135 us; speedup 1.0000x reference)
//
#include <hip/hip_runtime.h>

#define B_ 64
#define M_ 4096
#define D_ 128
#define O_ 16

typedef __bf16 bf16x8 __attribute__((ext_vector_type(8)));
typedef float  f32x4  __attribute__((ext_vector_type(4)));

// Single fused kernel. Block bid = b*32 + chunk.
// Phase 1 (producer): this block computes 64 u-values of u[b]
//   (o = chunk>>1, k = (chunk&1)*64 + j), u = x1[b]·W[o,:,k] + v2[o,k],
//   written in MFMA B-fragment order; publish via fence + device atomicAdd.
// Phase 2 (consumer): spin until all 32 sibling blocks published, then
//   stream x2 rows [chunk*128, +128) through mfma_f32_16x16x32_bf16 (R8 path).
__global__ __launch_bounds__(256, 6) void ntn_kernel(
    const float* __restrict__ x1, const float* __restrict__ x2,
    const float* __restrict__ W,  const float* __restrict__ V,
    const float* __restrict__ bias,
    __bf16* __restrict__ ub, int* __restrict__ flags,
    float* __restrict__ out)
{
    const int bid   = blockIdx.x;
    const int b     = bid >> 5;
    const int chunk = bid & 31;
    const int t     = threadIdx.x;

    __shared__ float x1s[D_];
    if (t < D_) x1s[t] = x1[b * D_ + t];
    __syncthreads();

    // ---------- phase 1: produce this block's 64 u-values ----------
    {
        const int o     = chunk >> 1;
        const int kbase = (chunk & 1) * 64;
        const int j     = t >> 2;       // 0..63 -> k = kbase + j
        const int q     = t & 3;        // d-quarter [q*32, q*32+32)
        const int k     = kbase + j;
        const float* Wp = W + ((size_t)o * D_ + q * 32) * D_ + k;
        float p = 0.f;
        #pragma unroll 8
        for (int dd = 0; dd < 32; ++dd)
            p = fmaf(x1s[q * 32 + dd], Wp[(size_t)dd * D_], p);
        p += __shfl_xor(p, 1, 64);
        p += __shfl_xor(p, 2, 64);
        if (q == 0) {
            const float uval = p + V[o * 2 * D_ + D_ + k];   // + v2[o,k]
            const int e  = k & 7;
            const int g  = (k >> 3) & 3;
            const int kb = k >> 5;
            ub[(size_t)b * 2048 + kb * 512 + g * 128 + o * 8 + e] = (__bf16)uval;
        }
        __syncthreads();                 // all 4 waves' writes issued
        if (t == 0) {
            __threadfence();             // device-scope release of u writes
            atomicAdd(&flags[b], 1);
        }
    }

    const int wave = t >> 6, lane = t & 63;
    const int rc = lane & 15;            // A-row / C-col (o)
    const int g  = lane >> 4;            // k-group

    // ---------- c inline (overlaps producer skew): bias + x1.v1 ----------
    float cv = bias[rc];
    #pragma unroll 8
    for (int k = 0; k < D_; ++k)
        cv = fmaf(x1s[k], V[rc * 2 * D_ + k], cv);

    // ---------- wait for full u[b] ----------
    if (t == 0) {
        while (__hip_atomic_load(&flags[b], __ATOMIC_ACQUIRE,
                                 __HIP_MEMORY_SCOPE_AGENT) < 32)
            __builtin_amdgcn_s_sleep(1);
    }
    __syncthreads();

    // ---------- phase 2: MFMA stream (verified R8 structure) ----------
    const bf16x8* uf = (const bf16x8*)(ub + (size_t)b * 2048);
    bf16x8 bfrag[4];
    #pragma unroll
    for (int kb = 0; kb < 4; ++kb) bfrag[kb] = uf[kb * 64 + lane];

    const int m_base = chunk * 128 + wave * 32;

    #pragma unroll
    for (int tt = 0; tt < 2; ++tt) {
        const int m0 = m_base + tt * 16;
        const float4* ap = (const float4*)(x2 + ((size_t)b * M_ + m0 + rc) * D_) + g * 2;

        float4 c0 = ap[0], c1 = ap[1];
        f32x4 acc = {cv, cv, cv, cv};
        #pragma unroll
        for (int kb = 0; kb < 4; ++kb) {
            float4 n0, n1;
            if (kb < 3) { n0 = ap[(kb + 1) * 8]; n1 = ap[(kb + 1) * 8 + 1]; }
            bf16x8 af;
            af[0] = (__bf16)c0.x; af[1] = (__bf16)c0.y;
            af[2] = (__bf16)c0.z; af[3] = (__bf16)c0.w;
            af[4] = (__bf16)c1.x; af[5] = (__bf16)c1.y;
            af[6] = (__bf16)c1.z; af[7] = (__bf16)c1.w;
            acc = __builtin_amdgcn_mfma_f32_16x16x32_bf16(af, bfrag[kb], acc, 0, 0, 0);
            c0 = n0; c1 = n1;
        }

        // C/D: col = lane&15 (=o), row = g*4 + i  (verified m89/m91)
        float* op = out + ((size_t)b * M_ + m0) * O_ + rc;
        #pragma unroll
        for (int i = 0; i < 4; ++i)
            __builtin_nontemporal_store(fmaxf(acc[i], 0.f), &op[(g * 4 + i) * O_]);
    }
}

extern "C" void kernel_launch(void* const* d_in, const int* in_sizes, int n_in,
                              void* d_out, int out_size, void* d_ws, size_t ws_size,
                              hipStream_t stream) {
    const float* x1   = (const float*)d_in[0];
    const float* x2   = (const float*)d_in[1];
    const float* W    = (const float*)d_in[2];
    const float* V    = (const float*)d_in[3];
    const float* bias = (const float*)d_in[4];
    float* out = (float*)d_out;

    __bf16* ubf  = (__bf16*)d_ws;                               // 256 KB
    int*    flgs = (int*)((char*)d_ws + (size_t)B_ * 2048 * sizeof(__bf16));

    hipMemsetAsync(flgs, 0, B_ * sizeof(int), stream);          // reset flags
    ntn_kernel<<<dim3(B_ * 32), 256, 0, stream>>>(x1, x2, W, V, bias,
                                                  ubf, flgs, out);
}

// Round 10
// 33.009 us; speedup vs baseline: 3.6092x; 3.6092x over previous
//
#include <hip/hip_runtime.h>

#define B_ 64
#define M_ 4096
#define D_ 128
#define O_ 16

typedef __bf16 bf16x8 __attribute__((ext_vector_type(8)));
typedef __bf16 bf16x4 __attribute__((ext_vector_type(4)));
typedef float  f32x4  __attribute__((ext_vector_type(4)));

// Pass 1: u[b,k,o] = sum_d x1[b,d]*W[o,d,k] + v2[o,k], emitted as bf16 in
// MFMA B-fragment order: lane = kgroup*16 + o, k = kb*32 + kgroup*8 + e.
//         c[b,o] = x1[b].v1[o] + bias[o]
// Vectorized: thread (kq,h) accumulates float4 over d in [h*32,h*32+32);
// per wave-instr the W read is one full 512B row. LDS tree combines the
// 4 d-strips; 32 threads emit bf16x4 fragments.
__global__ __launch_bounds__(128) void prep_kernel(
    const float* __restrict__ x1, const float* __restrict__ W,
    const float* __restrict__ V, const float* __restrict__ bias,
    __bf16* __restrict__ ub, float* __restrict__ c)
{
    const int o = blockIdx.x;   // [0,16)
    const int b = blockIdx.y;   // [0,64)
    const int t = threadIdx.x;  // [0,128)
    __shared__ float  x1s[D_];
    __shared__ float4 red4[128];
    __shared__ float  redc[2];
    x1s[t] = x1[b * D_ + t];
    __syncthreads();

    const int kq = t & 31;      // k-quad: k = 4*kq .. 4*kq+3
    const int h  = t >> 5;      // d-strip [h*32, h*32+32)
    const float4* Wp = (const float4*)(W + ((size_t)o * D_ + h * 32) * D_) + kq;
    float4 acc = {0.f, 0.f, 0.f, 0.f};
    #pragma unroll 8
    for (int dd = 0; dd < 32; ++dd) {
        const float xs = x1s[h * 32 + dd];
        const float4 w = Wp[dd * (D_ / 4)];
        acc.x = fmaf(xs, w.x, acc.x);
        acc.y = fmaf(xs, w.y, acc.y);
        acc.z = fmaf(xs, w.z, acc.z);
        acc.w = fmaf(xs, w.w, acc.w);
    }
    red4[t] = acc;

    // c partial: thread t handles k=t
    float p = x1s[t] * V[o * 2 * D_ + t];
    #pragma unroll
    for (int off = 32; off; off >>= 1) p += __shfl_down(p, off, 64);
    if ((t & 63) == 0) redc[t >> 6] = p;
    __syncthreads();

    if (t < 32) {
        float4 s0 = red4[t], s1 = red4[t + 32], s2 = red4[t + 64], s3 = red4[t + 96];
        const int k0 = 4 * t;
        const float* v2p = V + o * 2 * D_ + D_ + k0;
        bf16x4 uv;
        uv[0] = (__bf16)(s0.x + s1.x + s2.x + s3.x + v2p[0]);
        uv[1] = (__bf16)(s0.y + s1.y + s2.y + s3.y + v2p[1]);
        uv[2] = (__bf16)(s0.z + s1.z + s2.z + s3.z + v2p[2]);
        uv[3] = (__bf16)(s0.w + s1.w + s2.w + s3.w + v2p[3]);
        const int e0 = k0 & 7;
        const int g  = (k0 >> 3) & 3;
        const int kb = k0 >> 5;
        *(bf16x4*)(ub + (size_t)b * 2048 + kb * 512 + g * 128 + o * 8 + e0) = uv;
    }
    if (t == 0) c[b * O_ + o] = redc[0] + redc[1] + bias[o];
}

// Pass 2: out[b,m,o] = relu( x2[b,m,:] x u[b,:,:] + c[b,o] ) via MFMA.
// R7 structure (best measured): single-wave blocks, 2 tiles/wave, no LDS,
// no barriers. Output via non-temporal stores: out has zero reuse, keep it
// from evicting x2 (partially L3-resident across replays, per R9 FETCH).
__global__ __launch_bounds__(64, 7) void fused_kernel(
    const float* __restrict__ x2, const __bf16* __restrict__ ub,
    const float* __restrict__ c, float* __restrict__ out)
{
    const int b = blockIdx.y;
    const int lane = threadIdx.x;      // 0..63
    const int rc = lane & 15;          // A-row / C-col (o)
    const int g  = lane >> 4;          // k-group

    // B-fragments straight from global: 1KB/wave-instr coalesced, L2-hot.
    const bf16x8* uf = (const bf16x8*)(ub + (size_t)b * 2048);
    bf16x8 bfrag[4];
    #pragma unroll
    for (int kb = 0; kb < 4; ++kb) bfrag[kb] = uf[kb * 64 + lane];
    const float cv = c[b * O_ + rc];

    const int m_base = blockIdx.x * 32;

    #pragma unroll
    for (int tt = 0; tt < 2; ++tt) {
        const int m0 = m_base + tt * 16;
        // lane reads x2[b][m0+rc][g*8 + kb*32 .. +7]: per instr the wave
        // covers 16 rows x one 128B chunk each, fully coalesced.
        const float4* ap = (const float4*)(x2 + ((size_t)b * M_ + m0 + rc) * D_) + g * 2;
        float4 a[8];
        #pragma unroll
        for (int kb = 0; kb < 4; ++kb) {
            a[kb * 2]     = ap[kb * 8];
            a[kb * 2 + 1] = ap[kb * 8 + 1];
        }

        f32x4 acc = {cv, cv, cv, cv};
        #pragma unroll
        for (int kb = 0; kb < 4; ++kb) {
            const float* p0 = (const float*)&a[kb * 2];
            bf16x8 af;
            af[0] = (__bf16)p0[0]; af[1] = (__bf16)p0[1];
            af[2] = (__bf16)p0[2]; af[3] = (__bf16)p0[3];
            af[4] = (__bf16)p0[4]; af[5] = (__bf16)p0[5];
            af[6] = (__bf16)p0[6]; af[7] = (__bf16)p0[7];
            acc = __builtin_amdgcn_mfma_f32_16x16x32_bf16(af, bfrag[kb], acc, 0, 0, 0);
        }

        // C/D: col = lane&15 (=o), row = g*4 + i  (verified m89/m91)
        // Store instr i covers rows {m0+g*4+i} x 16 cols = 4 full 64B sectors.
        float* op = out + ((size_t)b * M_ + m0) * O_ + rc;
        #pragma unroll
        for (int i = 0; i < 4; ++i)
            __builtin_nontemporal_store(fmaxf(acc[i], 0.f), &op[(g * 4 + i) * O_]);
    }
}

extern "C" void kernel_launch(void* const* d_in, const int* in_sizes, int n_in,
                              void* d_out, int out_size, void* d_ws, size_t ws_size,
                              hipStream_t stream) {
    const float* x1   = (const float*)d_in[0];
    const float* x2   = (const float*)d_in[1];
    const float* W    = (const float*)d_in[2];
    const float* V    = (const float*)d_in[3];
    const float* bias = (const float*)d_in[4];
    float* out = (float*)d_out;

    __bf16* ubf = (__bf16*)d_ws;                           // 64*2048 bf16 = 256 KB
    float*  c   = (float*)((char*)d_ws + (size_t)B_ * 2048 * sizeof(__bf16));

    prep_kernel<<<dim3(O_, B_), 128, 0, stream>>>(x1, W, V, bias, ubf, c);
    fused_kernel<<<dim3(M_ / 32, B_), 64, 0, stream>>>(x2, ubf, c, out);
}